// Round 7
// baseline (436.024 us; speedup 1.0000x reference)
//
#include <hip/hip_runtime.h>

// BasalGanglia fused kernel (MI355X / gfx950), R7.
// R6 evidence: 55% stall @ 8 waves/CU, 4 barriers/iter, wave imbalance.
// R7: LSTM/vgpi chain decoupled onto a lag-1 consumer wave (vstn double-
// buffered), 11 producer waves x 2 tiles, 2 barriers/iter, 12 waves/CU.

typedef _Float16 f16_t;
typedef _Float16 f16x8 __attribute__((ext_vector_type(8)));
typedef _Float16 f16x4 __attribute__((ext_vector_type(4)));
typedef float floatx4 __attribute__((ext_vector_type(4)));

#define BTOT 8192
#define BM   32
#define NTHR 768     // 12 waves: 0..10 producers, 11 consumer
#define NBLK 256
#define VSTR 328     // f16 stride; dword stride 164 -> uniform bank spread
#define XST  32

struct Params {
  const float *stimulus, *deltavf, *hx0, *cx0;
  const float *w_vf0, *b_vf0, *w_vf1, *b_vf1, *w_vf2, *b_vf2, *w_vf3, *b_vf3;
  const float *w_jd1, *b_jd1, *w_jd2, *b_jd2, *w_kd1, *b_kd1, *w_kd2, *b_kd2;
  const float *w_sg, *b_sg, *w_gs, *b_gs, *w_glat, *b_glat, *w_slat, *b_slat;
  const float *w_d1gpi, *b_d1gpi, *w_stngpi, *b_stngpi;
  const float *w_ih, *b_ih, *w_hh, *b_hh;
  float* out;
};

struct __align__(16) Smem {
  f16_t vstn[2][BM * VSTR];     // 41984 B (double buffer: recurrence + lag-1 consumer)
  f16_t xgpe[2][BM * XST];      // 4096
  f16_t hxf[BM * XST];          // 2048 (consumer-private after init)
  f16_t wB2[21 * 512];          // 21504: t<19 gs A-frag, t=19/20 glat A-frag
  f16_t wsp[10 * 512];          // 10240: stngpi A-frags
  f16_t whh[5 * 512];           // 5120: w_hh A-frags
  union { float h1f[BM * 128]; float scr[3200]; float gates[BM * 80]; } u; // 16384
  float h0f[BM * 64];           // 8192
  float V_D2f[BM * 20];         // 2560
  float bsumS[304];             // b_slat+b_gs
  float bsg[20];                // b_sg+b_glat
  float bihh[80], wih0[80], wih1[80];
  float DPs[BM * 2], vgpis[BM * 2], lamS[BM];
};

__device__ __forceinline__ float rcp_f(float x) { return __builtin_amdgcn_rcpf(x); }
__device__ __forceinline__ float sigm_fast(float x) { return rcp_f(1.f + __expf(-x)); }
__device__ __forceinline__ float tanh_fast(float x) { return 1.f - 2.f * rcp_f(1.f + __expf(2.f * x)); }

__device__ __forceinline__ f16x8 ldfrag(const float* row, int k0, int kmax, bool valid) {
  float4 z = make_float4(0.f, 0.f, 0.f, 0.f);
  int nv = valid ? (kmax - k0) : 0;
  float4 f0 = (nv >= 4) ? *(const float4*)(row + k0) : z;
  float4 f1 = (nv >= 8) ? *(const float4*)(row + k0 + 4) : z;
  f16x8 r;
  r[0] = (f16_t)f0.x; r[1] = (f16_t)f0.y; r[2] = (f16_t)f0.z; r[3] = (f16_t)f0.w;
  r[4] = (f16_t)f1.x; r[5] = (f16_t)f1.y; r[6] = (f16_t)f1.z; r[7] = (f16_t)f1.w;
  return r;
}

__global__ __launch_bounds__(NTHR, 3) void bg_main(Params P) {
  __shared__ Smem S;
  const int tid  = threadIdx.x;
  const int lane = tid & 63;
  const int wv   = tid >> 6;      // 0..11
  const int q    = lane >> 4;
  const int cl   = lane & 15;
  const int row0 = blockIdx.x * BM;
  const floatx4 zf = {0.f, 0.f, 0.f, 0.f};

  // ================= init + weight-frag staging =================
  if (tid < BM) S.lamS[tid] = sigm_fast(P.deltavf[row0 + tid]);
  for (int i = tid; i < BM * 2; i += NTHR) S.vgpis[i] = 0.f;
  for (int i = tid; i < 2 * BM * VSTR; i += NTHR) ((f16_t*)S.vstn)[i] = (f16_t)0.f;
  for (int i = tid; i < 2 * BM * XST; i += NTHR) ((f16_t*)S.xgpe)[i] = (f16_t)0.f;
  for (int i = tid; i < BM * XST; i += NTHR) {
    int m = i >> 5, j = i & 31;
    S.hxf[i] = (j < 20) ? (f16_t)P.hx0[row0 * 20 + m * 20 + j] : (f16_t)0.f;
  }
  for (int i = tid; i < 21 * 512; i += NTHR) {        // gs / glat A-frags
    int t = i >> 9, l = (i >> 3) & 63, jj = i & 7;
    int c2 = l & 15, k = ((l >> 4) << 3) + jj;
    float v = 0.f;
    if (t < 19) { int n = t * 16 + c2; if (n < 300 && k < 20) v = P.w_gs[n * 20 + k]; }
    else        { int g = (t - 19) * 16 + c2; if (g < 20 && k < 20) v = P.w_glat[g * 20 + k]; }
    S.wB2[i] = (f16_t)v;
  }
  for (int i = tid; i < 10 * 512; i += NTHR) {        // stngpi A-frags
    int c = i >> 9, l = (i >> 3) & 63, jj = i & 7;
    int p = l & 15, k = c * 32 + ((l >> 4) << 3) + jj;
    S.wsp[i] = (f16_t)((p < 2 && k < 300) ? P.w_stngpi[p * 300 + k] : 0.f);
  }
  for (int i = tid; i < 5 * 512; i += NTHR) {         // w_hh A-frags
    int t = i >> 9, l = (i >> 3) & 63, jj = i & 7;
    int g = t * 16 + (l & 15), k = ((l >> 4) << 3) + jj;
    S.whh[i] = (f16_t)((k < 20) ? P.w_hh[g * 20 + k] : 0.f);
  }
  for (int i = tid; i < 304; i += NTHR) S.bsumS[i] = (i < 300) ? (P.b_slat[i] + P.b_gs[i]) : 0.f;
  for (int i = tid; i < 20; i += NTHR)  S.bsg[i] = P.b_sg[i] + P.b_glat[i];
  for (int i = tid; i < 80; i += NTHR) {
    S.bihh[i] = P.b_ih[i] + P.b_hh[i];
    S.wih0[i] = P.w_ih[i * 2 + 0];
    S.wih1[i] = P.w_ih[i * 2 + 1];
  }

  if (tid < 512) { // h0 = relu(stim @ w_vf0^T + b)
    int o = tid & 63, mb = (tid >> 6) * 4;
    const float4* wr = (const float4*)(P.w_vf0 + o * 300);
    float bias = P.b_vf0[o], a[4];
#pragma unroll
    for (int u = 0; u < 4; ++u) a[u] = bias;
    for (int kq = 0; kq < 75; ++kq) {
      float4 w = wr[kq];
#pragma unroll
      for (int u = 0; u < 4; ++u) {
        float4 v = *(const float4*)(P.stimulus + (size_t)(row0 + mb + u) * 300 + kq * 4);
        a[u] = fmaf(v.x, w.x, a[u]); a[u] = fmaf(v.y, w.y, a[u]);
        a[u] = fmaf(v.z, w.z, a[u]); a[u] = fmaf(v.w, w.w, a[u]);
      }
    }
#pragma unroll
    for (int u = 0; u < 4; ++u) S.h0f[(mb + u) * 64 + o] = fmaxf(a[u], 0.f);
  }
  __syncthreads();
  if (tid < 512) { // h1
    int o = tid & 127, mb = (tid >> 7) * 8;
    const float* wr = P.w_vf1 + o * 64;
    float bias = P.b_vf1[o], a[8];
#pragma unroll
    for (int u = 0; u < 8; ++u) a[u] = bias;
    for (int k = 0; k < 64; ++k) {
      float w = wr[k];
#pragma unroll
      for (int u = 0; u < 8; ++u) a[u] = fmaf(S.h0f[(mb + u) * 64 + k], w, a[u]);
    }
#pragma unroll
    for (int u = 0; u < 8; ++u) S.u.h1f[(mb + u) * 128 + o] = fmaxf(a[u], 0.f);
  }
  __syncthreads();
  if (tid < 512) { // h2 -> h0f
    int o = tid & 63, mb = (tid >> 6) * 4;
    const float* wr = P.w_vf2 + o * 128;
    float bias = P.b_vf2[o], a[4];
#pragma unroll
    for (int u = 0; u < 4; ++u) a[u] = bias;
    for (int k = 0; k < 128; ++k) {
      float w = wr[k];
#pragma unroll
      for (int u = 0; u < 4; ++u) a[u] = fmaf(S.u.h1f[(mb + u) * 128 + k], w, a[u]);
    }
#pragma unroll
    for (int u = 0; u < 4; ++u) S.h0f[(mb + u) * 64 + o] = fmaxf(a[u], 0.f);
  }
  __syncthreads();
  if (tid < 512) { // drives -> scr[0:2560); vt output
    int oid = tid & 127, mb = (tid >> 7) * 8;
    if (oid < 80) {
      int which = oid / 20, o = oid - which * 20;
      const float *wp, *bp;
      if (which == 0)      { wp = P.w_jd1; bp = P.b_jd1; }
      else if (which == 1) { wp = P.w_jd2; bp = P.b_jd2; }
      else if (which == 2) { wp = P.w_kd1; bp = P.b_kd1; }
      else                 { wp = P.w_kd2; bp = P.b_kd2; }
      float bias = bp[o], a[8];
#pragma unroll
      for (int u = 0; u < 8; ++u) a[u] = bias;
      for (int kq = 0; kq < 75; ++kq) {
        float4 w = *(const float4*)(wp + o * 300 + kq * 4);
#pragma unroll
        for (int u = 0; u < 8; ++u) {
          float4 v = *(const float4*)(P.stimulus + (size_t)(row0 + mb + u) * 300 + kq * 4);
          a[u] = fmaf(v.x, w.x, a[u]); a[u] = fmaf(v.y, w.y, a[u]);
          a[u] = fmaf(v.z, w.z, a[u]); a[u] = fmaf(v.w, w.w, a[u]);
        }
      }
#pragma unroll
      for (int u = 0; u < 8; ++u) S.u.scr[which * 640 + (mb + u) * 20 + o] = a[u];
    }
    if (tid < BM) {
      float a = P.b_vf3[0];
      for (int k = 0; k < 64; ++k) a = fmaf(S.h0f[tid * 64 + k], P.w_vf3[k], a);
      P.out[(size_t)BTOT * 20 + row0 + tid] = tanh_fast(a);
    }
  }
  __syncthreads();
  for (int i = tid; i < BM * 20; i += NTHR) { // FF -> V_D1 scr[2560:), V_D2f
    int m = i / 20;
    float j1 = S.u.scr[i],        j2 = S.u.scr[640 + i];
    float k1 = S.u.scr[1280 + i], k2 = S.u.scr[1920 + i];
    float L = S.lamS[m], v1 = 0.f, v2 = 0.f;
    for (int s = 0; s < 20; ++s) {
      v1 = sigm_fast(L * (j1 * (1.f - v1) + (1.f - k1) * v1));
      v2 = sigm_fast(L * (j2 * (1.f - v2) + (1.f - k2) * v2));
    }
    S.u.scr[2560 + i] = v1;
    S.V_D2f[i] = v2;
  }
  __syncthreads();
  if (tid < BM * 2) { // V_GPi_DP
    int m = tid >> 1, p2 = tid & 1;
    float a = P.b_d1gpi[p2];
    for (int o = 0; o < 20; ++o) a = fmaf(S.u.scr[2560 + m * 20 + o], P.w_d1gpi[p2 * 20 + o], a);
    S.DPs[tid] = a;
  }
  __syncthreads(); // scr dead; u.gates live from here

  // ================= per-wave setup =================
  // Producers (wv 0..10): tiles tA = wv (slat, n<176), tB = wv+11 (slat for
  // wv<=7, sg for wv=8/9, none for wv=10). A-frags register-resident.
  f16x8 WsA[10], WsB[10];
  const int tA = wv, tB = wv + 11;
  if (wv < 11) {
#pragma unroll
    for (int c = 0; c < 10; ++c)
      WsA[c] = ldfrag(P.w_slat + (size_t)(tA * 16 + cl) * 300, c * 32 + q * 8, 300, true);
    if (wv <= 7) {
      int n = tB * 16 + cl;
#pragma unroll
      for (int c = 0; c < 10; ++c)
        WsB[c] = ldfrag(P.w_slat + (size_t)(n < 300 ? n : 0) * 300, c * 32 + q * 8, 300, n < 300);
    } else if (wv <= 9) {
      int g = (tB - 19) * 16 + cl;
#pragma unroll
      for (int c = 0; c < 10; ++c)
        WsB[c] = ldfrag(P.w_sg + (size_t)(g < 20 ? g : 0) * 300, c * 32 + q * 8, 300, g < 20);
    }
  }
  const float bstn0 = P.b_stngpi[0], bstn1 = P.b_stngpi[1];
  float xsA[2][4], xsB[2][4];
#pragma unroll
  for (int mf = 0; mf < 2; ++mf)
#pragma unroll
    for (int r = 0; r < 4; ++r) { xsA[mf][r] = 0.f; xsB[mf][r] = 0.f; }

  // Consumer (wv 11): lane owns batch m = lane>>1, gate half j0 = (lane&1)*10.
  const int cm = lane >> 1, cj0 = (lane & 1) * 10;
  float cxr[10], hxr[10];
  if (wv == 11) {
#pragma unroll
    for (int u = 0; u < 10; ++u) {
      cxr[u] = P.cx0[row0 * 20 + lane * 10 + u];
      hxr[u] = P.hx0[row0 * 20 + lane * 10 + u];
    }
  }

  // consumer part 1: stngpi MFMA -> vgpi update; gates MFMA (+bias/w_ih fold)
  auto consume1 = [&](int po_) {
    floatx4 ip0 = zf, ip1 = zf;
#pragma unroll
    for (int c = 0; c < 10; ++c) {
      f16x8 Wp = *(const f16x8*)&S.wsp[c * 512 + lane * 8];
      f16x8 b0 = *(const f16x8*)&S.vstn[po_][cl * VSTR + c * 32 + q * 8];
      f16x8 b1 = *(const f16x8*)&S.vstn[po_][(16 + cl) * VSTR + c * 32 + q * 8];
      ip0 = __builtin_amdgcn_mfma_f32_16x16x32_f16(Wp, b0, ip0, 0, 0, 0);
      ip1 = __builtin_amdgcn_mfma_f32_16x16x32_f16(Wp, b1, ip1, 0, 0, 0);
    }
    if (q == 0) {
#pragma unroll
      for (int mf = 0; mf < 2; ++mf) {
        int batch = cl + 16 * mf;
        float lm = S.lamS[batch];
#pragma unroll
        for (int p = 0; p < 2; ++p) {
          float raw = (mf ? ip1[p] : ip0[p]) + (p ? bstn1 : bstn0);
          int idx = batch * 2 + p;
          float v = S.vgpis[idx];
          v = v + 0.1f * (-v - S.DPs[idx] + 2.f * (lm * raw));
          S.vgpis[idx] = v;
        }
      }
    }
    // gates: D[g][batch] = w_hh @ hx(prev); fold bias + w_ih*(-vgpi) at store
    f16x8 h0 = *(const f16x8*)&S.hxf[cl * XST + q * 8];
    f16x8 h1 = *(const f16x8*)&S.hxf[(16 + cl) * XST + q * 8];
    float vA0 = S.vgpis[cl * 2], vA1 = S.vgpis[cl * 2 + 1];
    float vB0 = S.vgpis[(cl + 16) * 2], vB1 = S.vgpis[(cl + 16) * 2 + 1];
#pragma unroll
    for (int gt = 0; gt < 5; ++gt) {
      f16x8 Wh = *(const f16x8*)&S.whh[gt * 512 + lane * 8];
      floatx4 gA = __builtin_amdgcn_mfma_f32_16x16x32_f16(Wh, h0, zf, 0, 0, 0);
      floatx4 gB = __builtin_amdgcn_mfma_f32_16x16x32_f16(Wh, h1, zf, 0, 0, 0);
      int gb = gt * 16 + q * 4;
      floatx4 bi = *(const floatx4*)&S.bihh[gb];
      floatx4 w0 = *(const floatx4*)&S.wih0[gb];
      floatx4 w1 = *(const floatx4*)&S.wih1[gb];
#pragma unroll
      for (int r = 0; r < 4; ++r) {
        gA[r] += bi[r] - w0[r] * vA0 - w1[r] * vA1;
        gB[r] += bi[r] - w0[r] * vB0 - w1[r] * vB1;
      }
      *(floatx4*)&S.u.gates[cl * 80 + gb] = gA;
      *(floatx4*)&S.u.gates[(cl + 16) * 80 + gb] = gB;
    }
  };
  // consumer part 2: LSTM pointwise, one batch row per lane (10 elems)
  auto consume2 = [&]() {
#pragma unroll
    for (int u = 0; u < 10; ++u) {
      int j = cj0 + u;
      float gi = S.u.gates[cm * 80 + j];
      float gf = S.u.gates[cm * 80 + 20 + j];
      float gg = S.u.gates[cm * 80 + 40 + j];
      float go = S.u.gates[cm * 80 + 60 + j];
      float cn = sigm_fast(gf) * cxr[u] + sigm_fast(gi) * tanh_fast(gg);
      cxr[u] = cn;
      float hn = sigm_fast(go) * tanh_fast(cn);
      hxr[u] = hn;
      S.hxf[cm * XST + j] = (f16_t)hn;
    }
  };

  // ================= 50 slots, 2 barriers each =================
  for (int it = 0; it < 50; ++it) {
    const int po = it & 1, pn = po ^ 1;
    floatx4 aA[2], aB[2];
    aA[0] = zf; aA[1] = zf; aB[0] = zf; aB[1] = zf;
    if (wv < 11) {
      // Phase A: [slat|sg] @ vstn[po] (+ glat @ xgpe[po] for sg tiles)
#pragma unroll
      for (int c = 0; c < 10; ++c) {
        f16x8 b0 = *(const f16x8*)&S.vstn[po][cl * VSTR + c * 32 + q * 8];
        f16x8 b1 = *(const f16x8*)&S.vstn[po][(16 + cl) * VSTR + c * 32 + q * 8];
        aA[0] = __builtin_amdgcn_mfma_f32_16x16x32_f16(WsA[c], b0, aA[0], 0, 0, 0);
        aA[1] = __builtin_amdgcn_mfma_f32_16x16x32_f16(WsA[c], b1, aA[1], 0, 0, 0);
        if (wv <= 9) {
          aB[0] = __builtin_amdgcn_mfma_f32_16x16x32_f16(WsB[c], b0, aB[0], 0, 0, 0);
          aB[1] = __builtin_amdgcn_mfma_f32_16x16x32_f16(WsB[c], b1, aB[1], 0, 0, 0);
        }
      }
      if (wv == 8 || wv == 9) { // sg tiles: + glat @ xgpe[po], write xgpe[pn]
        f16x8 Wg = *(const f16x8*)&S.wB2[tB * 512 + lane * 8];
        f16x8 g0 = *(const f16x8*)&S.xgpe[po][cl * XST + q * 8];
        f16x8 g1 = *(const f16x8*)&S.xgpe[po][(16 + cl) * XST + q * 8];
        aB[0] = __builtin_amdgcn_mfma_f32_16x16x32_f16(Wg, g0, aB[0], 0, 0, 0);
        aB[1] = __builtin_amdgcn_mfma_f32_16x16x32_f16(Wg, g1, aB[1], 0, 0, 0);
        int g0i = (tB - 19) * 16 + q * 4;
        if (g0i < 20) {
          floatx4 bg4 = *(const floatx4*)&S.bsg[g0i];
#pragma unroll
          for (int mf = 0; mf < 2; ++mf) {
            int batch = cl + 16 * mf;
            floatx4 vd4 = *(const floatx4*)&S.V_D2f[batch * 20 + g0i];
            f16x4 pk;
#pragma unroll
            for (int r = 0; r < 4; ++r) pk[r] = (f16_t)(aB[mf][r] + bg4[r] - vd4[r]);
            *(f16x4*)&S.xgpe[pn][batch * XST + g0i] = pk;
          }
        }
      }
    } else if (it > 0) {
      consume1(po);
    }
    __syncthreads(); // b1: xgpe[pn] ready

    if (wv < 11) {
      // Phase B: slat tiles += gs @ xgpe[pn]; xstn update -> vstn[pn]
      f16x8 x0 = *(const f16x8*)&S.xgpe[pn][cl * XST + q * 8];
      f16x8 x1 = *(const f16x8*)&S.xgpe[pn][(16 + cl) * XST + q * 8];
      { // tile tA (always slat, n < 176: no bounds)
        f16x8 Wg = *(const f16x8*)&S.wB2[tA * 512 + lane * 8];
        aA[0] = __builtin_amdgcn_mfma_f32_16x16x32_f16(Wg, x0, aA[0], 0, 0, 0);
        aA[1] = __builtin_amdgcn_mfma_f32_16x16x32_f16(Wg, x1, aA[1], 0, 0, 0);
        int n0 = tA * 16 + q * 4;
        floatx4 bs4 = *(const floatx4*)&S.bsumS[n0];
#pragma unroll
        for (int mf = 0; mf < 2; ++mf) {
          float lm = S.lamS[cl + 16 * mf];
          f16x4 pk;
#pragma unroll
          for (int r = 0; r < 4; ++r) {
            float xo = xsA[mf][r];
            float xn = xo + (1.0f / 3.0f) * (aA[mf][r] + bs4[r] - xo);
            xsA[mf][r] = xn;
            pk[r] = (f16_t)tanh_fast(lm * xn);
          }
          *(f16x4*)&S.vstn[pn][(cl + 16 * mf) * VSTR + n0] = pk;
        }
      }
      if (wv <= 7) { // tile tB slat
        f16x8 Wg = *(const f16x8*)&S.wB2[tB * 512 + lane * 8];
        aB[0] = __builtin_amdgcn_mfma_f32_16x16x32_f16(Wg, x0, aB[0], 0, 0, 0);
        aB[1] = __builtin_amdgcn_mfma_f32_16x16x32_f16(Wg, x1, aB[1], 0, 0, 0);
        int n0 = tB * 16 + q * 4;
        if (!(tB == 18 && q == 3)) { // n0..n0+3 < 300
          floatx4 bs4 = *(const floatx4*)&S.bsumS[n0];
#pragma unroll
          for (int mf = 0; mf < 2; ++mf) {
            float lm = S.lamS[cl + 16 * mf];
            f16x4 pk;
#pragma unroll
            for (int r = 0; r < 4; ++r) {
              float xo = xsB[mf][r];
              float xn = xo + (1.0f / 3.0f) * (aB[mf][r] + bs4[r] - xo);
              xsB[mf][r] = xn;
              pk[r] = (f16_t)tanh_fast(lm * xn);
            }
            *(f16x4*)&S.vstn[pn][(cl + 16 * mf) * VSTR + n0] = pk;
          }
        }
      }
    } else if (it > 0) {
      consume2();
    }
    __syncthreads(); // b2: vstn[pn] ready; consumer done with vstn[po]
  }

  // tail: consumer processes ref-iter 49 (vstn(50) lives in buffer 0)
  if (wv == 11) {
    consume1(0);
    consume2();
#pragma unroll
    for (int u = 0; u < 10; ++u)
      P.out[(size_t)row0 * 20 + lane * 10 + u] = hxr[u];
  }
}

extern "C" void kernel_launch(void* const* d_in, const int* in_sizes, int n_in,
                              void* d_out, int out_size, void* d_ws, size_t ws_size,
                              hipStream_t stream) {
  (void)in_sizes; (void)n_in; (void)out_size; (void)d_ws; (void)ws_size;
  Params P;
  P.stimulus = (const float*)d_in[0];
  P.deltavf  = (const float*)d_in[1];
  P.hx0 = (const float*)d_in[2];
  P.cx0 = (const float*)d_in[3];
  P.w_vf0 = (const float*)d_in[4];  P.b_vf0 = (const float*)d_in[5];
  P.w_vf1 = (const float*)d_in[6];  P.b_vf1 = (const float*)d_in[7];
  P.w_vf2 = (const float*)d_in[8];  P.b_vf2 = (const float*)d_in[9];
  P.w_vf3 = (const float*)d_in[10]; P.b_vf3 = (const float*)d_in[11];
  P.w_jd1 = (const float*)d_in[12]; P.b_jd1 = (const float*)d_in[13];
  P.w_jd2 = (const float*)d_in[14]; P.b_jd2 = (const float*)d_in[15];
  P.w_kd1 = (const float*)d_in[16]; P.b_kd1 = (const float*)d_in[17];
  P.w_kd2 = (const float*)d_in[18]; P.b_kd2 = (const float*)d_in[19];
  P.w_sg  = (const float*)d_in[20]; P.b_sg  = (const float*)d_in[21];
  P.w_gs  = (const float*)d_in[22]; P.b_gs  = (const float*)d_in[23];
  P.w_glat= (const float*)d_in[24]; P.b_glat= (const float*)d_in[25];
  P.w_slat= (const float*)d_in[26]; P.b_slat= (const float*)d_in[27];
  P.w_d1gpi  = (const float*)d_in[28]; P.b_d1gpi  = (const float*)d_in[29];
  P.w_stngpi = (const float*)d_in[30]; P.b_stngpi = (const float*)d_in[31];
  P.w_ih = (const float*)d_in[32]; P.b_ih = (const float*)d_in[33];
  P.w_hh = (const float*)d_in[34]; P.b_hh = (const float*)d_in[35];
  P.out  = (float*)d_out;
  bg_main<<<NBLK, NTHR, 0, stream>>>(P);
}